// Round 6
// baseline (544.623 us; speedup 1.0000x reference)
//
#include <hip/hip_runtime.h>

// Fused LSTM(78->8, T=64) + FC(8->16) + ReLU + FC(16->11) + softmax. B=16384.
// R6: DPP-based recurrence (quad_perm gate gather + mirror/ror8 h exchange,
// all direction-unambiguous), scalar-FMA projection with b128 weight quads,
// float4 global->LDS staging. Lane map: lane = row(5:4)|pr(3:2)|type(1:0).
// Occupancy is decomposition-capped at 16 waves/CU (4096 waves total), so
// this round attacks chain latency + instruction count, not occupancy.

typedef float v2f __attribute__((ext_vector_type(2)));

#define B_SZ 16384
#define T_SZ 64
#define IN_SZ 78
#define H_SZ 8
#define NCLS 11
#define NB 16              // rows per block
#define TT 4               // timesteps per tile
#define NTHREADS 256
#define NITER (T_SZ / TT)  // 16
#define ROWSTR (T_SZ * IN_SZ)   // 4992 floats per batch row in x
#define ROWF (TT * IN_SZ)       // 312 floats per row per tile (contiguous!)
#define TILE_F4 (NB * ROWF / 4) // 1248 float4 per tile

__device__ __forceinline__ float sigm(float x) { return 1.0f / (1.0f + __expf(-x)); }

template<int CTRL>
__device__ __forceinline__ float dpp_f(float x) {
    return __int_as_float(__builtin_amdgcn_update_dpp(
        0, __float_as_int(x), CTRL, 0xF, 0xF, true));
}
template<int CTRL>
__device__ __forceinline__ v2f dpp2(v2f v) {
    v2f r; r.x = dpp_f<CTRL>(v.x); r.y = dpp_f<CTRL>(v.y); return r;
}
// DPP controls: quad_perm broadcast q -> q*0x55; row_ror:8 = 0x128 (lane^8);
// row_mirror = 0x140 (lane^15); row_half_mirror = 0x141 (lane^7).

__global__ __launch_bounds__(NTHREADS, 4)
void lstm_fused(const float* __restrict__ x,
                const float* __restrict__ W_ih,
                const float* __restrict__ W_hh,
                const float* __restrict__ b_ih,
                const float* __restrict__ b_hh,
                const float* __restrict__ W1,
                const float* __restrict__ b1,
                const float* __restrict__ W2,
                const float* __restrict__ b2,
                float* __restrict__ out)
{
    __shared__ float x2f[NB * ROWF];      // [row][t][k], 4992 floats = 19968 B
    __shared__ float Wq[39 * 16 * 4];     // [kp][lane16][4]: {W[G0][2kp],W[G0][2kp+1],W[G1][2kp],W[G1][2kp+1]}
    __shared__ float z1s[NB][17];

    const int tid  = threadIdx.x;
    const int type = tid & 3;             // 0:i 1:f 2:g 3:o (quad position)
    const int pr   = (tid >> 2) & 3;      // hidden-unit pair: j in {2pr, 2pr+1}
    const int rr   = tid >> 4;            // row 0..15 (4 per wave)
    const int u    = tid & 15;            // lane16 id; also classifier unit id
    const bool isT = (type == 2);

    const size_t rowbase = (size_t)blockIdx.x * NB;
    const float* xb = x + rowbase * ROWSTR;
    const float4* xb4 = (const float4*)xb;

    // ---- per-lane constants ----
    const int G0 = type * 8 + 2 * pr;     // gate index in [0,32)
    const int G1 = G0 + 1;
    v2f bias; bias.x = b_ih[G0] + b_hh[G0]; bias.y = b_ih[G1] + b_hh[G1];
    // WhhP[m] pairs with hrot[m] = h-pair (pr^m)
    float4 WhhP[4];
    #pragma unroll
    for (int m = 0; m < 4; ++m) {
        int p = pr ^ m;
        WhhP[m].x = W_hh[G0 * H_SZ + 2 * p];
        WhhP[m].y = W_hh[G0 * H_SZ + 2 * p + 1];
        WhhP[m].z = W_hh[G1 * H_SZ + 2 * p];
        WhhP[m].w = W_hh[G1 * H_SZ + 2 * p + 1];
    }

    // ---- staging offsets: 5 rounds of float4, p = tid + 256*j in [0,1248) ----
    // p = row*78 + q ; global float4 off = row*1248 + it*78 + q
    int og[5];
    {
        int r0 = tid / IN_SZ;             // 0..3
        int q  = tid - r0 * IN_SZ;
        int oo = r0 * 1248 + q;
        #pragma unroll
        for (int j = 0; j < 5; ++j) {
            og[j] = oo;
            q += 22; oo += 3766;                      // +3 rows, +22 quads
            if (q >= IN_SZ) { q -= IN_SZ; oo += 1170; } // quad wrap -> +1 row
        }
    }

    // ---- prologue: issue x tile 0 loads, stage Wq, publish tile 0 ----
    float4 xv[5];
    #pragma unroll
    for (int j = 0; j < 4; ++j) xv[j] = xb4[og[j]];
    if (tid < 224)              xv[4] = xb4[og[4]];

    for (int i = tid; i < 39 * 64; i += NTHREADS) {
        int e = i & 3, gl = (i >> 2) & 15, kp = i >> 6;
        int ty = gl & 3, pp = gl >> 2;
        int G = ty * 8 + 2 * pp + (e >> 1);
        int k = 2 * kp + (e & 1);
        Wq[i] = W_ih[G * IN_SZ + k];
    }

    float4* x2_4 = (float4*)x2f;
    #pragma unroll
    for (int j = 0; j < 4; ++j) x2_4[tid + j * NTHREADS] = xv[j];
    if (tid < 224)              x2_4[tid + 4 * NTHREADS] = xv[4];
    __syncthreads();

    // ---- LSTM state ----
    v2f c2; c2.x = 0.f; c2.y = 0.f;
    v2f hrot[4];                          // hrot[m] = h-pair (pr^m)
    #pragma unroll
    for (int m = 0; m < 4; ++m) { hrot[m].x = 0.f; hrot[m].y = 0.f; }

    const v2f*    x2v = (const v2f*)x2f;
    const float4* wq4 = (const float4*)Wq;
    float accx[TT], accy[TT];

    // ---- projection of tile 0 ----
    #pragma unroll
    for (int tt = 0; tt < TT; ++tt) { accx[tt] = bias.x; accy[tt] = bias.y; }
    #pragma unroll 13
    for (int kp = 0; kp < 39; ++kp) {
        float4 wv = wq4[kp * 16 + u];
        #pragma unroll
        for (int tt = 0; tt < TT; ++tt) {
            v2f xk = x2v[rr * 156 + tt * 39 + kp];
            accx[tt] = fmaf(xk.x, wv.x, accx[tt]);
            accx[tt] = fmaf(xk.y, wv.y, accx[tt]);
            accy[tt] = fmaf(xk.x, wv.z, accy[tt]);
            accy[tt] = fmaf(xk.y, wv.w, accy[tt]);
        }
    }

    // one LSTM timestep from preactivation (vx, vy); updates c2, hrot
    auto lstm_step = [&](float vx, float vy) {
        #pragma unroll
        for (int m = 0; m < 4; ++m) {
            vx = fmaf(hrot[m].x, WhhP[m].x, vx);
            vx = fmaf(hrot[m].y, WhhP[m].y, vx);
            vy = fmaf(hrot[m].x, WhhP[m].z, vy);
            vy = fmaf(hrot[m].y, WhhP[m].w, vy);
        }
        v2f a;
        {
            float ax = isT ? 2.0f * vx : vx;
            float ay = isT ? 2.0f * vy : vy;
            float sx = sigm(ax), sy = sigm(ay);
            a.x = isT ? 2.0f * sx - 1.0f : sx;
            a.y = isT ? 2.0f * sy - 1.0f : sy;
        }
        v2f i2 = dpp2<0x00>(a);   // quad_perm[0,0,0,0] -> i-pair
        v2f f2 = dpp2<0x55>(a);   // f-pair
        v2f g2 = dpp2<0xAA>(a);   // g-pair (tanh'd by its lane)
        v2f o2 = dpp2<0xFF>(a);   // o-pair
        c2.x = fmaf(f2.x, c2.x, i2.x * g2.x);
        c2.y = fmaf(f2.y, c2.y, i2.y * g2.y);
        v2f th;
        th.x = 2.0f * sigm(2.0f * c2.x) - 1.0f;
        th.y = 2.0f * sigm(2.0f * c2.y) - 1.0f;
        v2f h2; h2.x = o2.x * th.x; h2.y = o2.y * th.y;   // h-pair pr (type-invariant)
        hrot[0] = h2;
        hrot[1] = dpp2<0x141>(h2);   // row_half_mirror: pair pr^1
        hrot[2] = dpp2<0x128>(h2);   // row_ror:8      : pair pr^2
        hrot[3] = dpp2<0x140>(h2);   // row_mirror     : pair pr^3
    };

    // ---- main pipeline ----
    for (int it = 1; it < NITER; ++it) {
        const float4* xit4 = xb4 + it * 78;
        #pragma unroll
        for (int j = 0; j < 4; ++j) xv[j] = xit4[og[j]];
        if (tid < 224)              xv[4] = xit4[og[4]];

        #pragma unroll
        for (int tt = 0; tt < TT; ++tt) lstm_step(accx[tt], accy[tt]);

        __syncthreads();
        #pragma unroll
        for (int j = 0; j < 4; ++j) x2_4[tid + j * NTHREADS] = xv[j];
        if (tid < 224)              x2_4[tid + 4 * NTHREADS] = xv[4];
        __syncthreads();

        #pragma unroll
        for (int tt = 0; tt < TT; ++tt) { accx[tt] = bias.x; accy[tt] = bias.y; }
        #pragma unroll 13
        for (int kp = 0; kp < 39; ++kp) {
            float4 wv = wq4[kp * 16 + u];
            #pragma unroll
            for (int tt = 0; tt < TT; ++tt) {
                v2f xk = x2v[rr * 156 + tt * 39 + kp];
                accx[tt] = fmaf(xk.x, wv.x, accx[tt]);
                accx[tt] = fmaf(xk.y, wv.y, accx[tt]);
                accy[tt] = fmaf(xk.x, wv.z, accy[tt]);
                accy[tt] = fmaf(xk.y, wv.w, accy[tt]);
            }
        }
    }
    #pragma unroll
    for (int tt = 0; tt < TT; ++tt) lstm_step(accx[tt], accy[tt]);

    // ---- classifier: lane computes hidden unit u for its row ----
    {
        float z1 = b1[u];
        #pragma unroll
        for (int m = 0; m < 4; ++m) {
            int p = pr ^ m;
            z1 += fmaxf(hrot[m].x, 0.0f) * W1[u * H_SZ + 2 * p];
            z1 += fmaxf(hrot[m].y, 0.0f) * W1[u * H_SZ + 2 * p + 1];
        }
        z1s[rr][u] = fmaxf(z1, 0.0f);
    }
    __syncthreads();
    if (tid < NB) {
        const int row = tid;
        float z1v[16];
        #pragma unroll
        for (int uu = 0; uu < 16; ++uu) z1v[uu] = z1s[row][uu];
        float z2[NCLS];
        float m = -1e30f;
        #pragma unroll
        for (int c = 0; c < NCLS; ++c) {
            float v = b2[c];
            #pragma unroll
            for (int uu = 0; uu < 16; ++uu) v += z1v[uu] * W2[c * 16 + uu];
            z2[c] = v;
            m = fmaxf(m, v);
        }
        float s = 0.0f;
        #pragma unroll
        for (int c = 0; c < NCLS; ++c) { z2[c] = __expf(z2[c] - m); s += z2[c]; }
        float inv = 1.0f / s;
        float* op = out + (rowbase + row) * NCLS;
        #pragma unroll
        for (int c = 0; c < NCLS; ++c) op[c] = z2[c] * inv;
    }
}

extern "C" void kernel_launch(void* const* d_in, const int* in_sizes, int n_in,
                              void* d_out, int out_size, void* d_ws, size_t ws_size,
                              hipStream_t stream) {
    const float* x    = (const float*)d_in[0];
    const float* W_ih = (const float*)d_in[1];
    const float* W_hh = (const float*)d_in[2];
    const float* b_ih = (const float*)d_in[3];
    const float* b_hh = (const float*)d_in[4];
    const float* W1   = (const float*)d_in[5];
    const float* b1   = (const float*)d_in[6];
    const float* W2   = (const float*)d_in[7];
    const float* b2   = (const float*)d_in[8];
    float* outp = (float*)d_out;

    lstm_fused<<<dim3(B_SZ / NB), dim3(NTHREADS), 0, stream>>>(
        x, W_ih, W_hh, b_ih, b_hh, W1, b1, W2, b2, outp);
}

// Round 8
// 530.338 us; speedup vs baseline: 1.0269x; 1.0269x over previous
//
#include <hip/hip_runtime.h>

// Fused LSTM(78->8, T=64) + FC(8->16) + ReLU + FC(16->11) + softmax. B=16384.
// R7/R8 = R6 (DPP recurrence + scalar-FMA projection + float4 staging) with
// the scratch-spill fixed: projection unroll 13->3, and unconditional 5-round
// staging into a padded LDS tile (no divergent tail -> xv stays in VGPRs).
// Lane map: lane = row(5:4)|pr(3:2)|type(1:0). Occupancy capped at 16
// waves/CU by decomposition (4096 waves total).
// (R8 = resubmission of R7; GPU acquisition timed out, kernel never ran.)

typedef float v2f __attribute__((ext_vector_type(2)));

#define B_SZ 16384
#define T_SZ 64
#define IN_SZ 78
#define H_SZ 8
#define NCLS 11
#define NB 16              // rows per block
#define TT 4               // timesteps per tile
#define NTHREADS 256
#define NITER (T_SZ / TT)  // 16
#define ROWSTR (T_SZ * IN_SZ)   // 4992 floats per batch row in x
#define ROWF (TT * IN_SZ)       // 312 floats per row per tile (contiguous)
#define TILE_F4 (NB * ROWF / 4) // 1248 float4 per tile
#define TILE_F4_PAD 1280        // padded: slots [1248,1280) are write-only

__device__ __forceinline__ float sigm(float x) { return 1.0f / (1.0f + __expf(-x)); }

template<int CTRL>
__device__ __forceinline__ float dpp_f(float x) {
    return __int_as_float(__builtin_amdgcn_update_dpp(
        0, __float_as_int(x), CTRL, 0xF, 0xF, true));
}
template<int CTRL>
__device__ __forceinline__ v2f dpp2(v2f v) {
    v2f r; r.x = dpp_f<CTRL>(v.x); r.y = dpp_f<CTRL>(v.y); return r;
}
// DPP controls: quad_perm broadcast q -> q*0x55; row_ror:8 = 0x128 (lane^8);
// row_mirror = 0x140 (lane^15); row_half_mirror = 0x141 (lane^7).

__global__ __launch_bounds__(NTHREADS, 4)
void lstm_fused(const float* __restrict__ x,
                const float* __restrict__ W_ih,
                const float* __restrict__ W_hh,
                const float* __restrict__ b_ih,
                const float* __restrict__ b_hh,
                const float* __restrict__ W1,
                const float* __restrict__ b1,
                const float* __restrict__ W2,
                const float* __restrict__ b2,
                float* __restrict__ out)
{
    __shared__ float x2f[TILE_F4_PAD * 4]; // [row][t][k] + pad, 20480 B
    __shared__ float Wq[39 * 16 * 4];      // [kp][lane16][4]
    __shared__ float z1s[NB][17];

    const int tid  = threadIdx.x;
    const int type = tid & 3;             // 0:i 1:f 2:g 3:o (quad position)
    const int pr   = (tid >> 2) & 3;      // hidden-unit pair: j in {2pr, 2pr+1}
    const int rr   = tid >> 4;            // row 0..15 (4 per wave)
    const int u    = tid & 15;            // lane16 id; also classifier unit id
    const bool isT = (type == 2);

    const size_t rowbase = (size_t)blockIdx.x * NB;
    const float* xb = x + rowbase * ROWSTR;
    const float4* xb4 = (const float4*)xb;

    // ---- per-lane constants ----
    const int G0 = type * 8 + 2 * pr;     // gate index in [0,32)
    const int G1 = G0 + 1;
    v2f bias; bias.x = b_ih[G0] + b_hh[G0]; bias.y = b_ih[G1] + b_hh[G1];
    float4 WhhP[4];                       // WhhP[m] pairs with hrot[m] = pair (pr^m)
    #pragma unroll
    for (int m = 0; m < 4; ++m) {
        int p = pr ^ m;
        WhhP[m].x = W_hh[G0 * H_SZ + 2 * p];
        WhhP[m].y = W_hh[G0 * H_SZ + 2 * p + 1];
        WhhP[m].z = W_hh[G1 * H_SZ + 2 * p];
        WhhP[m].w = W_hh[G1 * H_SZ + 2 * p + 1];
    }

    // ---- staging offsets: 5 rounds of float4, p = tid + 256*j in [0,1248) ----
    // p = row*78 + q ; global float4 off = row*1248 + q (it term via pointer)
    int og[5];
    {
        int r0 = tid / IN_SZ;             // 0..3
        int q  = tid - r0 * IN_SZ;
        int oo = r0 * 1248 + q;
        #pragma unroll
        for (int j = 0; j < 5; ++j) {
            og[j] = oo;
            q += 22; oo += 3766;                      // +3 rows, +22 quads
            if (q >= IN_SZ) { q -= IN_SZ; oo += 1170; } // quad wrap -> +1 row
        }
        // threads >=224 would run past the tile at j=4; re-load og[3] into
        // the write-only LDS padding instead (no divergent liveness).
        if (tid >= 224) og[4] = og[3];
    }

    // ---- prologue: issue x tile 0 loads, stage Wq, publish tile 0 ----
    float4 xv[5];
    #pragma unroll
    for (int j = 0; j < 5; ++j) xv[j] = xb4[og[j]];

    for (int i = tid; i < 39 * 64; i += NTHREADS) {
        int e = i & 3, gl = (i >> 2) & 15, kp = i >> 6;
        int ty = gl & 3, pp = gl >> 2;
        int G = ty * 8 + 2 * pp + (e >> 1);
        int k = 2 * kp + (e & 1);
        Wq[i] = W_ih[G * IN_SZ + k];
    }

    float4* x2_4 = (float4*)x2f;
    #pragma unroll
    for (int j = 0; j < 5; ++j) x2_4[tid + j * NTHREADS] = xv[j];
    __syncthreads();

    // ---- LSTM state ----
    v2f c2; c2.x = 0.f; c2.y = 0.f;
    v2f hrot[4];                          // hrot[m] = h-pair (pr^m)
    #pragma unroll
    for (int m = 0; m < 4; ++m) { hrot[m].x = 0.f; hrot[m].y = 0.f; }

    const v2f*    x2v = (const v2f*)x2f;
    const float4* wq4 = (const float4*)Wq;
    float accx[TT], accy[TT];

    // ---- projection of tile 0 ----
    #pragma unroll
    for (int tt = 0; tt < TT; ++tt) { accx[tt] = bias.x; accy[tt] = bias.y; }
    #pragma unroll 3
    for (int kp = 0; kp < 39; ++kp) {
        float4 wv = wq4[kp * 16 + u];
        #pragma unroll
        for (int tt = 0; tt < TT; ++tt) {
            v2f xk = x2v[rr * 156 + tt * 39 + kp];
            accx[tt] = fmaf(xk.x, wv.x, accx[tt]);
            accx[tt] = fmaf(xk.y, wv.y, accx[tt]);
            accy[tt] = fmaf(xk.x, wv.z, accy[tt]);
            accy[tt] = fmaf(xk.y, wv.w, accy[tt]);
        }
    }

    // one LSTM timestep from preactivation (vx, vy); updates c2, hrot
    auto lstm_step = [&](float vx, float vy) {
        #pragma unroll
        for (int m = 0; m < 4; ++m) {
            vx = fmaf(hrot[m].x, WhhP[m].x, vx);
            vx = fmaf(hrot[m].y, WhhP[m].y, vx);
            vy = fmaf(hrot[m].x, WhhP[m].z, vy);
            vy = fmaf(hrot[m].y, WhhP[m].w, vy);
        }
        v2f a;
        {
            float ax = isT ? 2.0f * vx : vx;
            float ay = isT ? 2.0f * vy : vy;
            float sx = sigm(ax), sy = sigm(ay);
            a.x = isT ? 2.0f * sx - 1.0f : sx;
            a.y = isT ? 2.0f * sy - 1.0f : sy;
        }
        v2f i2 = dpp2<0x00>(a);   // quad_perm[0,0,0,0] -> i-pair
        v2f f2 = dpp2<0x55>(a);   // f-pair
        v2f g2 = dpp2<0xAA>(a);   // g-pair (tanh'd by its lane)
        v2f o2 = dpp2<0xFF>(a);   // o-pair
        c2.x = fmaf(f2.x, c2.x, i2.x * g2.x);
        c2.y = fmaf(f2.y, c2.y, i2.y * g2.y);
        v2f th;
        th.x = 2.0f * sigm(2.0f * c2.x) - 1.0f;
        th.y = 2.0f * sigm(2.0f * c2.y) - 1.0f;
        v2f h2; h2.x = o2.x * th.x; h2.y = o2.y * th.y;   // h-pair pr (type-invariant)
        hrot[0] = h2;
        hrot[1] = dpp2<0x141>(h2);   // row_half_mirror: pair pr^1
        hrot[2] = dpp2<0x128>(h2);   // row_ror:8      : pair pr^2
        hrot[3] = dpp2<0x140>(h2);   // row_mirror     : pair pr^3
    };

    // ---- main pipeline ----
    for (int it = 1; it < NITER; ++it) {
        const float4* xit4 = xb4 + it * 78;
        #pragma unroll
        for (int j = 0; j < 5; ++j) xv[j] = xit4[og[j]];

        #pragma unroll
        for (int tt = 0; tt < TT; ++tt) lstm_step(accx[tt], accy[tt]);

        __syncthreads();
        #pragma unroll
        for (int j = 0; j < 5; ++j) x2_4[tid + j * NTHREADS] = xv[j];
        __syncthreads();

        #pragma unroll
        for (int tt = 0; tt < TT; ++tt) { accx[tt] = bias.x; accy[tt] = bias.y; }
        #pragma unroll 3
        for (int kp = 0; kp < 39; ++kp) {
            float4 wv = wq4[kp * 16 + u];
            #pragma unroll
            for (int tt = 0; tt < TT; ++tt) {
                v2f xk = x2v[rr * 156 + tt * 39 + kp];
                accx[tt] = fmaf(xk.x, wv.x, accx[tt]);
                accx[tt] = fmaf(xk.y, wv.y, accx[tt]);
                accy[tt] = fmaf(xk.x, wv.z, accy[tt]);
                accy[tt] = fmaf(xk.y, wv.w, accy[tt]);
            }
        }
    }
    #pragma unroll
    for (int tt = 0; tt < TT; ++tt) lstm_step(accx[tt], accy[tt]);

    // ---- classifier: lane computes hidden unit u for its row ----
    {
        float z1 = b1[u];
        #pragma unroll
        for (int m = 0; m < 4; ++m) {
            int p = pr ^ m;
            z1 += fmaxf(hrot[m].x, 0.0f) * W1[u * H_SZ + 2 * p];
            z1 += fmaxf(hrot[m].y, 0.0f) * W1[u * H_SZ + 2 * p + 1];
        }
        z1s[rr][u] = fmaxf(z1, 0.0f);
    }
    __syncthreads();
    if (tid < NB) {
        const int row = tid;
        float z1v[16];
        #pragma unroll
        for (int uu = 0; uu < 16; ++uu) z1v[uu] = z1s[row][uu];
        float z2[NCLS];
        float m = -1e30f;
        #pragma unroll
        for (int c = 0; c < NCLS; ++c) {
            float v = b2[c];
            #pragma unroll
            for (int uu = 0; uu < 16; ++uu) v += z1v[uu] * W2[c * 16 + uu];
            z2[c] = v;
            m = fmaxf(m, v);
        }
        float s = 0.0f;
        #pragma unroll
        for (int c = 0; c < NCLS; ++c) { z2[c] = __expf(z2[c] - m); s += z2[c]; }
        float inv = 1.0f / s;
        float* op = out + (rowbase + row) * NCLS;
        #pragma unroll
        for (int c = 0; c < NCLS; ++c) op[c] = z2[c] * inv;
    }
}

extern "C" void kernel_launch(void* const* d_in, const int* in_sizes, int n_in,
                              void* d_out, int out_size, void* d_ws, size_t ws_size,
                              hipStream_t stream) {
    const float* x    = (const float*)d_in[0];
    const float* W_ih = (const float*)d_in[1];
    const float* W_hh = (const float*)d_in[2];
    const float* b_ih = (const float*)d_in[3];
    const float* b_hh = (const float*)d_in[4];
    const float* W1   = (const float*)d_in[5];
    const float* b1   = (const float*)d_in[6];
    const float* W2   = (const float*)d_in[7];
    const float* b2   = (const float*)d_in[8];
    float* outp = (float*)d_out;

    lstm_fused<<<dim3(B_SZ / NB), dim3(NTHREADS), 0, stream>>>(
        x, W_ih, W_hh, b_ih, b_hh, W1, b1, W2, b2, outp);
}

// Round 10
// 521.146 us; speedup vs baseline: 1.0450x; 1.0176x over previous
//
#include <hip/hip_runtime.h>

// Fused LSTM(78->8, T=64) + FC(8->16) + ReLU + FC(16->11) + softmax. B=16384.
// R9/R10: eliminate register staging (the R6-R8 scratch-spill source) with
// global_load_lds DMA into a double-buffered LDS x-tile (1 barrier/iter),
// and move the weight-quad table into d_ws (prepacked by a tiny kernel,
// L1-resident) so the double buffer fits at 4 blocks/CU (40960 B LDS).
// DPP recurrence unchanged from R7/R8 (verified passing).
// Lane map: lane = row(5:4)|pr(3:2)|type(1:0).
// (R10 = resubmission of R9; GPU acquisition timed out, kernel never ran.)

typedef float v2f __attribute__((ext_vector_type(2)));

#define B_SZ 16384
#define T_SZ 64
#define IN_SZ 78
#define H_SZ 8
#define NCLS 11
#define NB 16              // rows per block
#define TT 4               // timesteps per tile
#define NTHREADS 256
#define NITER (T_SZ / TT)  // 16
#define ROWSTR (T_SZ * IN_SZ)   // 4992 floats per batch row in x
#define TILE_F4 1248            // float4 per tile (16 rows x 312 floats)
#define TILE_F4_PAD 1280        // slots [1248,1280) are write-only DMA pad

// ws layout (floats): wq[39*16*4] | whhq[16*4*4] | bias2[16*2]
#define WS_WQ   0
#define WS_WHH  2496
#define WS_BIAS 2752

__device__ __forceinline__ float sigm(float x) { return 1.0f / (1.0f + __expf(-x)); }

template<int CTRL>
__device__ __forceinline__ float dpp_f(float x) {
    return __int_as_float(__builtin_amdgcn_update_dpp(
        0, __float_as_int(x), CTRL, 0xF, 0xF, true));
}
template<int CTRL>
__device__ __forceinline__ v2f dpp2(v2f v) {
    v2f r; r.x = dpp_f<CTRL>(v.x); r.y = dpp_f<CTRL>(v.y); return r;
}

// async 16B global->LDS DMA; LDS dest = wave-uniform base + lane*16
__device__ __forceinline__ void dma16(const float4* g, float4* l) {
    __builtin_amdgcn_global_load_lds(
        (const __attribute__((address_space(1))) void*)g,
        (__attribute__((address_space(3))) void*)l,
        16, 0, 0);
}

// ---- prep kernel: pack weight quads / recurrence quads / bias into ws ----
__global__ __launch_bounds__(NTHREADS)
void prep_kernel(const float* __restrict__ W_ih,
                 const float* __restrict__ W_hh,
                 const float* __restrict__ b_ih,
                 const float* __restrict__ b_hh,
                 float* __restrict__ ws)
{
    const int tid = threadIdx.x;
    // wq[kp][u][4] = {W[G0][2kp], W[G0][2kp+1], W[G1][2kp], W[G1][2kp+1]}
    for (int i = tid; i < 39 * 16 * 4; i += NTHREADS) {
        int e = i & 3, u = (i >> 2) & 15, kp = i >> 6;
        int ty = u & 3, pp = u >> 2;
        int G = ty * 8 + 2 * pp + (e >> 1);
        int k = 2 * kp + (e & 1);
        ws[WS_WQ + i] = W_ih[G * IN_SZ + k];
    }
    // whhq[u][m][4] = {Whh[G0][2p], Whh[G0][2p+1], Whh[G1][2p], Whh[G1][2p+1]}, p = pr^m
    for (int i = tid; i < 16 * 4 * 4; i += NTHREADS) {
        int e = i & 3, m = (i >> 2) & 3, u = i >> 4;
        int ty = u & 3, pp = u >> 2;
        int p = pp ^ m;
        int G = ty * 8 + 2 * pp + (e >> 1);
        int j = 2 * p + (e & 1);
        ws[WS_WHH + i] = W_hh[G * H_SZ + j];
    }
    // bias2[u][2] = {b_ih+b_hh}[G0], [G1]
    if (tid < 32) {
        int e = tid & 1, u = tid >> 1;
        int ty = u & 3, pp = u >> 2;
        int G = ty * 8 + 2 * pp + e;
        ws[WS_BIAS + tid] = b_ih[G] + b_hh[G];
    }
}

__global__ __launch_bounds__(NTHREADS, 4)
void lstm_fused(const float* __restrict__ x,
                const float* __restrict__ ws,
                const float* __restrict__ W1,
                const float* __restrict__ b1,
                const float* __restrict__ W2,
                const float* __restrict__ b2,
                float* __restrict__ out)
{
    __shared__ float4 xbuf[2][TILE_F4_PAD];   // 40960 B total -> 4 blocks/CU

    const int tid  = threadIdx.x;
    const int type = tid & 3;             // 0:i 1:f 2:g 3:o
    const int pr   = (tid >> 2) & 3;      // hidden-unit pair
    const int rr   = tid >> 4;            // row 0..15
    const int u    = tid & 15;            // lane16 id
    const bool isT = (type == 2);

    const size_t rowbase = (size_t)blockIdx.x * NB;
    const float4* xb4 = (const float4*)(x + rowbase * ROWSTR);

    // ---- per-lane constants from ws ----
    v2f bias = *(const v2f*)&ws[WS_BIAS + 2 * u];
    float4 WhhP[4];
    #pragma unroll
    for (int m = 0; m < 4; ++m)
        WhhP[m] = *(const float4*)&ws[WS_WHH + u * 16 + m * 4];
    const float4* wq4 = (const float4*)&ws[WS_WQ];

    // ---- staging offsets: 5 DMA rounds, slot p = tid + 256*j in [0,1280) ----
    // p = row*78 + q ; global float4 off = row*1248 + q (+ it*78 via pointer)
    int og[5];
    {
        int r0 = tid / IN_SZ;
        int q  = tid - r0 * IN_SZ;
        int oo = r0 * 1248 + q;
        #pragma unroll
        for (int j = 0; j < 5; ++j) {
            og[j] = oo;
            q += 22; oo += 3766;                        // +3 rows, +22 quads
            if (q >= IN_SZ) { q -= IN_SZ; oo += 1170; } // quad wrap -> +1 row
        }
        if (tid >= 224) og[4] = og[3];   // round 4 tail -> valid addr, pad slot
    }
    const int wavebase = tid & 192;      // wave-uniform LDS slot base

    // ---- prologue: DMA tile 0 into buf0 ----
    #pragma unroll
    for (int j = 0; j < 5; ++j)
        dma16(xb4 + og[j], &xbuf[0][j * NTHREADS + wavebase]);
    __syncthreads();                      // drains DMA

    // ---- LSTM state ----
    v2f c2; c2.x = 0.f; c2.y = 0.f;
    v2f hrot[4];
    #pragma unroll
    for (int m = 0; m < 4; ++m) { hrot[m].x = 0.f; hrot[m].y = 0.f; }

    float accx[TT], accy[TT];

    auto do_proj = [&](const v2f* xtv) {
        #pragma unroll
        for (int tt = 0; tt < TT; ++tt) { accx[tt] = bias.x; accy[tt] = bias.y; }
        #pragma unroll 3
        for (int kp = 0; kp < 39; ++kp) {
            float4 wv = wq4[kp * 16 + u];
            #pragma unroll
            for (int tt = 0; tt < TT; ++tt) {
                v2f xk = xtv[rr * 156 + tt * 39 + kp];
                accx[tt] = fmaf(xk.x, wv.x, accx[tt]);
                accx[tt] = fmaf(xk.y, wv.y, accx[tt]);
                accy[tt] = fmaf(xk.x, wv.z, accy[tt]);
                accy[tt] = fmaf(xk.y, wv.w, accy[tt]);
            }
        }
    };

    auto lstm_step = [&](float vx, float vy) {
        #pragma unroll
        for (int m = 0; m < 4; ++m) {
            vx = fmaf(hrot[m].x, WhhP[m].x, vx);
            vx = fmaf(hrot[m].y, WhhP[m].y, vx);
            vy = fmaf(hrot[m].x, WhhP[m].z, vy);
            vy = fmaf(hrot[m].y, WhhP[m].w, vy);
        }
        v2f a;
        {
            float ax = isT ? 2.0f * vx : vx;
            float ay = isT ? 2.0f * vy : vy;
            float sx = sigm(ax), sy = sigm(ay);
            a.x = isT ? 2.0f * sx - 1.0f : sx;
            a.y = isT ? 2.0f * sy - 1.0f : sy;
        }
        v2f i2 = dpp2<0x00>(a);   // quad_perm broadcast -> i-pair
        v2f f2 = dpp2<0x55>(a);   // f-pair
        v2f g2 = dpp2<0xAA>(a);   // g-pair (already tanh)
        v2f o2 = dpp2<0xFF>(a);   // o-pair
        c2.x = fmaf(f2.x, c2.x, i2.x * g2.x);
        c2.y = fmaf(f2.y, c2.y, i2.y * g2.y);
        v2f th;
        th.x = 2.0f * sigm(2.0f * c2.x) - 1.0f;
        th.y = 2.0f * sigm(2.0f * c2.y) - 1.0f;
        v2f h2; h2.x = o2.x * th.x; h2.y = o2.y * th.y;
        hrot[0] = h2;
        hrot[1] = dpp2<0x141>(h2);   // row_half_mirror: pair pr^1
        hrot[2] = dpp2<0x128>(h2);   // row_ror:8      : pair pr^2
        hrot[3] = dpp2<0x140>(h2);   // row_mirror     : pair pr^3
    };

    // ---- main pipeline: 1 barrier per iteration ----
    for (int t = 0; t < NITER - 1; ++t) {
        // DMA tile t+1 into the other buffer (readers of it finished at the
        // barrier that ended iteration t-1)
        const float4* xsrc = xb4 + (t + 1) * 78;
        float4* dbuf = xbuf[(t + 1) & 1];
        #pragma unroll
        for (int j = 0; j < 5; ++j)
            dma16(xsrc + og[j], &dbuf[j * NTHREADS + wavebase]);

        do_proj((const v2f*)xbuf[t & 1]);
        #pragma unroll
        for (int tt = 0; tt < TT; ++tt) lstm_step(accx[tt], accy[tt]);

        __syncthreads();   // drains DMA (vmcnt) + closes buf[t&1] reads
    }
    do_proj((const v2f*)xbuf[(NITER - 1) & 1]);
    #pragma unroll
    for (int tt = 0; tt < TT; ++tt) lstm_step(accx[tt], accy[tt]);

    // ---- classifier: z1 staged in dead buf0 area ----
    float* z1f = (float*)&xbuf[0][0];     // [NB][17] overlay, 1088 B
    {
        float z1 = b1[u];
        #pragma unroll
        for (int m = 0; m < 4; ++m) {
            int p = pr ^ m;
            z1 += fmaxf(hrot[m].x, 0.0f) * W1[u * H_SZ + 2 * p];
            z1 += fmaxf(hrot[m].y, 0.0f) * W1[u * H_SZ + 2 * p + 1];
        }
        z1f[rr * 17 + u] = fmaxf(z1, 0.0f);
    }
    __syncthreads();
    if (tid < NB) {
        const int row = tid;
        float z1v[16];
        #pragma unroll
        for (int uu = 0; uu < 16; ++uu) z1v[uu] = z1f[row * 17 + uu];
        float z2[NCLS];
        float m = -1e30f;
        #pragma unroll
        for (int c = 0; c < NCLS; ++c) {
            float v = b2[c];
            #pragma unroll
            for (int uu = 0; uu < 16; ++uu) v += z1v[uu] * W2[c * 16 + uu];
            z2[c] = v;
            m = fmaxf(m, v);
        }
        float s = 0.0f;
        #pragma unroll
        for (int c = 0; c < NCLS; ++c) { z2[c] = __expf(z2[c] - m); s += z2[c]; }
        float inv = 1.0f / s;
        float* op = out + (rowbase + row) * NCLS;
        #pragma unroll
        for (int c = 0; c < NCLS; ++c) op[c] = z2[c] * inv;
    }
}

extern "C" void kernel_launch(void* const* d_in, const int* in_sizes, int n_in,
                              void* d_out, int out_size, void* d_ws, size_t ws_size,
                              hipStream_t stream) {
    const float* x    = (const float*)d_in[0];
    const float* W_ih = (const float*)d_in[1];
    const float* W_hh = (const float*)d_in[2];
    const float* b_ih = (const float*)d_in[3];
    const float* b_hh = (const float*)d_in[4];
    const float* W1   = (const float*)d_in[5];
    const float* b1   = (const float*)d_in[6];
    const float* W2   = (const float*)d_in[7];
    const float* b2   = (const float*)d_in[8];
    float* outp = (float*)d_out;
    float* ws   = (float*)d_ws;

    prep_kernel<<<dim3(1), dim3(NTHREADS), 0, stream>>>(W_ih, W_hh, b_ih, b_hh, ws);
    lstm_fused<<<dim3(B_SZ / NB), dim3(NTHREADS), 0, stream>>>(
        x, ws, W1, b1, W2, b2, outp);
}